// Round 8
// baseline (5084.846 us; speedup 1.0000x reference)
//
#include <hip/hip_runtime.h>
#include <hip/hip_bf16.h>
#include <math.h>

typedef float f4 __attribute__((ext_vector_type(4)));
typedef __attribute__((ext_vector_type(8))) short short8;

#define NTAGS 600
#define CEw   48
#define HH    256
#define TSEQ  96
#define CLW   16
#define LMAXD 24
#define NROWS 6144
#define DIN   192
#define VCD   200

__device__ __forceinline__ float sigf(float x){ return 1.0f/(1.0f+expf(-x)); }
__device__ __forceinline__ ushort bhi_u(float v){ __hip_bfloat16 h = __float2bfloat16(v); return *(ushort*)&h; }
__device__ __forceinline__ float ub_f(ushort u){ __hip_bfloat16 h = *(__hip_bfloat16*)&u; return __bfloat162float(h); }

// ============ generalized MFMA 3-term GEMM (per-segment staging; proven) ============
template<int ACT, int HS, int KK>
__global__ __launch_bounds__(256)
void gemm3_k(const ushort* __restrict__ Ahi, const ushort* __restrict__ Alo,
             const ushort* __restrict__ Bhi, const ushort* __restrict__ Blo,
             const float* __restrict__ bias, float* __restrict__ C,
             ushort* __restrict__ Hhi, ushort* __restrict__ Hlo,
             int Nc, int ldC)
{
    __shared__ __align__(16) ushort As[128 * 64];
    __shared__ __align__(16) ushort Bs[128 * 64];
    const int tid = threadIdx.x;
    const int m0 = blockIdx.x * 128;
    const int n0 = blockIdx.y * 128;
    const int w = tid >> 6, l = tid & 63;
    const int wr = (w >> 1) * 64, wc = (w & 1) * 64;
    f4 acc[4][4];
    #pragma unroll
    for (int i = 0; i < 4; ++i)
        #pragma unroll
        for (int j = 0; j < 4; ++j) acc[i][j] = (f4){0.f,0.f,0.f,0.f};

    #pragma unroll
    for (int seg = 0; seg < 3; ++seg) {
        const ushort* Ap = (seg == 1) ? Alo : Ahi;
        const ushort* Bp = (seg == 2) ? Blo : Bhi;
        #pragma unroll
        for (int kt = 0; kt < KK; kt += 64) {
            #pragma unroll
            for (int i = 0; i < 4; ++i) {
                int c = w * 4 + i;
                int row = c * 8 + (l >> 3);
                int col16 = l & 7;
                __builtin_amdgcn_global_load_lds(
                    (const __attribute__((address_space(1))) void*)(Ap + (size_t)(m0 + row) * KK + kt + col16 * 8),
                    (__attribute__((address_space(3))) void*)((char*)As + c * 1024 + l * 16), 16, 0, 0);
                __builtin_amdgcn_global_load_lds(
                    (const __attribute__((address_space(1))) void*)(Bp + (size_t)(n0 + row) * KK + kt + col16 * 8),
                    (__attribute__((address_space(3))) void*)((char*)Bs + c * 1024 + l * 16), 16, 0, 0);
            }
            __syncthreads();
            #pragma unroll
            for (int kk = 0; kk < 64; kk += 32) {
                short8 a[4], b[4];
                #pragma unroll
                for (int mf = 0; mf < 4; ++mf)
                    a[mf] = *(const short8*)(As + (wr + mf * 16 + (l & 15)) * 64 + kk + (l >> 4) * 8);
                #pragma unroll
                for (int nf = 0; nf < 4; ++nf)
                    b[nf] = *(const short8*)(Bs + (wc + nf * 16 + (l & 15)) * 64 + kk + (l >> 4) * 8);
                #pragma unroll
                for (int mf = 0; mf < 4; ++mf)
                    #pragma unroll
                    for (int nf = 0; nf < 4; ++nf)
                        acc[mf][nf] = __builtin_amdgcn_mfma_f32_16x16x32_bf16(a[mf], b[nf], acc[mf][nf], 0, 0, 0);
            }
            __syncthreads();
        }
    }
    #pragma unroll
    for (int nf = 0; nf < 4; ++nf) {
        int n = n0 + wc + nf * 16 + (l & 15);
        if (n >= Nc) continue;
        float bv = bias[n];
        #pragma unroll
        for (int mf = 0; mf < 4; ++mf) {
            int mrow = m0 + wr + mf * 16 + (l >> 4) * 4;
            #pragma unroll
            for (int q2 = 0; q2 < 4; ++q2) {
                float v = acc[mf][nf][q2] + bv;
                if (ACT == 1) v = tanhf(v);
                size_t o = (size_t)(mrow + q2) * ldC + n;
                C[o] = v;
                if (HS) {
                    ushort hi = bhi_u(v);
                    Hhi[o] = hi;
                    Hlo[o] = bhi_u(v - ub_f(hi));
                }
            }
        }
    }
}

// ============ priming GEMM: gh_0 = h @ whh^T (K=256), writes gh only ============
__global__ __launch_bounds__(256)
void gemmC_k(const ushort* __restrict__ Ahi, const ushort* __restrict__ Alo,
             const ushort* __restrict__ Bhi, const ushort* __restrict__ Blo,
             const float* __restrict__ bias, float* __restrict__ gh)
{
    __shared__ __align__(16) ushort AsH[128 * 64];
    __shared__ __align__(16) ushort AsL[128 * 64];
    __shared__ __align__(16) ushort BsH[128 * 64];
    __shared__ __align__(16) ushort BsL[128 * 64];
    const int tid = threadIdx.x;
    const int m0 = blockIdx.x * 128;
    const int n0 = blockIdx.y * 128;
    const int w = tid >> 6, l = tid & 63;
    const int wr = (w >> 1) * 64, wc = (w & 1) * 64;
    f4 acc[4][4];
    #pragma unroll
    for (int i = 0; i < 4; ++i)
        #pragma unroll
        for (int j = 0; j < 4; ++j) acc[i][j] = (f4){0.f,0.f,0.f,0.f};

    #pragma unroll
    for (int kt = 0; kt < 256; kt += 64) {
        #pragma unroll
        for (int i = 0; i < 4; ++i) {
            int c = w * 4 + i;
            int row = c * 8 + (l >> 3);
            int col16 = l & 7;
            size_t ga = (size_t)(m0 + row) * 256 + kt + col16 * 8;
            size_t gb = (size_t)(n0 + row) * 256 + kt + col16 * 8;
            int loff = c * 1024 + l * 16;
            __builtin_amdgcn_global_load_lds(
                (const __attribute__((address_space(1))) void*)(Ahi + ga),
                (__attribute__((address_space(3))) void*)((char*)AsH + loff), 16, 0, 0);
            __builtin_amdgcn_global_load_lds(
                (const __attribute__((address_space(1))) void*)(Alo + ga),
                (__attribute__((address_space(3))) void*)((char*)AsL + loff), 16, 0, 0);
            __builtin_amdgcn_global_load_lds(
                (const __attribute__((address_space(1))) void*)(Bhi + gb),
                (__attribute__((address_space(3))) void*)((char*)BsH + loff), 16, 0, 0);
            __builtin_amdgcn_global_load_lds(
                (const __attribute__((address_space(1))) void*)(Blo + gb),
                (__attribute__((address_space(3))) void*)((char*)BsL + loff), 16, 0, 0);
        }
        __syncthreads();
        #pragma unroll
        for (int kk = 0; kk < 64; kk += 32) {
            short8 ah[4], al[4], bh[4], bl[4];
            #pragma unroll
            for (int mf = 0; mf < 4; ++mf) {
                int off = (wr + mf * 16 + (l & 15)) * 64 + kk + (l >> 4) * 8;
                ah[mf] = *(const short8*)(AsH + off);
                al[mf] = *(const short8*)(AsL + off);
            }
            #pragma unroll
            for (int nf = 0; nf < 4; ++nf) {
                int off = (wc + nf * 16 + (l & 15)) * 64 + kk + (l >> 4) * 8;
                bh[nf] = *(const short8*)(BsH + off);
                bl[nf] = *(const short8*)(BsL + off);
            }
            #pragma unroll
            for (int mf = 0; mf < 4; ++mf)
                #pragma unroll
                for (int nf = 0; nf < 4; ++nf) {
                    acc[mf][nf] = __builtin_amdgcn_mfma_f32_16x16x32_bf16(ah[mf], bh[nf], acc[mf][nf], 0, 0, 0);
                    acc[mf][nf] = __builtin_amdgcn_mfma_f32_16x16x32_bf16(al[mf], bh[nf], acc[mf][nf], 0, 0, 0);
                    acc[mf][nf] = __builtin_amdgcn_mfma_f32_16x16x32_bf16(ah[mf], bl[nf], acc[mf][nf], 0, 0, 0);
                }
        }
        __syncthreads();
    }
    #pragma unroll
    for (int nf = 0; nf < 4; ++nf) {
        int col = n0 + wc + nf * 16 + (l & 15);
        float bv = bias[col];
        #pragma unroll
        for (int mf = 0; mf < 4; ++mf) {
            int mrow = m0 + wr + mf * 16 + (l >> 4) * 4;
            #pragma unroll
            for (int q2 = 0; q2 < 4; ++q2)
                gh[(size_t)(mrow + q2) * 768 + col] = acc[mf][nf][q2] + bv;
        }
    }
}

// ============ fused decode step: update(32 rows by blocks n0<4) -> flag sync -> GEMM ============
// grid dim3(48,8). flags[m0] reaches 4*(s+1) when the m-tile's h planes are fresh.
__global__ __launch_bounds__(256)
void dec_k(float* __restrict__ gh, const float* __restrict__ git,
           float* __restrict__ out_lem,
           ushort* __restrict__ hhi, ushort* __restrict__ hlo,
           const ushort* __restrict__ Bhi, const ushort* __restrict__ Blo,
           const float* __restrict__ bias, int* __restrict__ flags, int s)
{
    __shared__ __align__(16) ushort AsH[128 * 64];
    __shared__ __align__(16) ushort AsL[128 * 64];
    __shared__ __align__(16) ushort BsH[128 * 64];
    __shared__ __align__(16) ushort BsL[128 * 64];
    __shared__ int sprev[32];
    const int tid = threadIdx.x;
    const int mb = blockIdx.x;
    const int m0 = mb * 128;
    const int n0b = blockIdx.y;
    const int n0 = n0b * 128;

    // ---- prologue: blocks n0b<4 update rows [m0+n0b*32, +32) ----
    if (n0b < 4) {
        const int r0 = m0 + n0b * 32;
        if (s > 0) {
            const float* lemP = out_lem + (size_t)(s - 1) * VCD;
            int rl = tid >> 3, c = tid & 7;
            const float* L = lemP + (size_t)(r0 + rl) * (LMAXD * VCD);
            float best = -3.4e38f; int bi = 0;
            for (int i = c; i < VCD; i += 8) {
                float v = L[i];
                if (v > best) { best = v; bi = i; }
            }
            #pragma unroll
            for (int d = 1; d < 8; d <<= 1) {
                float ov = __shfl_xor(best, d);
                int   oi = __shfl_xor(bi, d);
                if (ov > best || (ov == best && oi < bi)) { best = ov; bi = oi; }
            }
            if (c == 0) sprev[rl] = bi;
        } else if (tid < 32) sprev[tid] = 3;   // BOS
        __syncthreads();
        #pragma unroll 4
        for (int i = 0; i < 32; ++i) {
            int row = r0 + i;
            int j = tid;
            const float* g  = gh + (size_t)row * 768;
            const float* gi = git + (size_t)sprev[i] * 768;
            float r  = sigf(gi[j] + g[j]);
            float z  = sigf(gi[256 + j] + g[256 + j]);
            float nn = tanhf(gi[512 + j] + r * g[512 + j]);
            size_t o = (size_t)row * 256 + j;
            float hold = ub_f(hhi[o]) + ub_f(hlo[o]);
            float hv = (1.0f - z) * nn + z * hold;
            ushort hi = bhi_u(hv);
            hhi[o] = hi;
            hlo[o] = bhi_u(hv - ub_f(hi));
        }
        __threadfence();
        __syncthreads();
        if (tid == 0)
            __hip_atomic_fetch_add(&flags[mb], 1, __ATOMIC_RELEASE, __HIP_MEMORY_SCOPE_AGENT);
    }

    // ---- spin until this m-tile's planes are fresh ----
    if (tid == 0) {
        while (__hip_atomic_load(&flags[mb], __ATOMIC_ACQUIRE, __HIP_MEMORY_SCOPE_AGENT) < 4 * (s + 1))
            __builtin_amdgcn_s_sleep(1);
    }
    __syncthreads();
    __threadfence();

    // ---- GEMM: [gh_next | logits_s] = h_new @ [whh | proj]^T ----
    const int w = tid >> 6, l = tid & 63;
    const int wr = (w >> 1) * 64, wc = (w & 1) * 64;
    f4 acc[4][4];
    #pragma unroll
    for (int i = 0; i < 4; ++i)
        #pragma unroll
        for (int j = 0; j < 4; ++j) acc[i][j] = (f4){0.f,0.f,0.f,0.f};

    #pragma unroll
    for (int kt = 0; kt < 256; kt += 64) {
        #pragma unroll
        for (int i = 0; i < 4; ++i) {
            int c = w * 4 + i;
            int row = c * 8 + (l >> 3);
            int col16 = l & 7;
            size_t ga = (size_t)(m0 + row) * 256 + kt + col16 * 8;
            size_t gb = (size_t)(n0 + row) * 256 + kt + col16 * 8;
            int loff = c * 1024 + l * 16;
            __builtin_amdgcn_global_load_lds(
                (const __attribute__((address_space(1))) void*)(hhi + ga),
                (__attribute__((address_space(3))) void*)((char*)AsH + loff), 16, 0, 0);
            __builtin_amdgcn_global_load_lds(
                (const __attribute__((address_space(1))) void*)(hlo + ga),
                (__attribute__((address_space(3))) void*)((char*)AsL + loff), 16, 0, 0);
            __builtin_amdgcn_global_load_lds(
                (const __attribute__((address_space(1))) void*)(Bhi + gb),
                (__attribute__((address_space(3))) void*)((char*)BsH + loff), 16, 0, 0);
            __builtin_amdgcn_global_load_lds(
                (const __attribute__((address_space(1))) void*)(Blo + gb),
                (__attribute__((address_space(3))) void*)((char*)BsL + loff), 16, 0, 0);
        }
        __syncthreads();
        #pragma unroll
        for (int kk = 0; kk < 64; kk += 32) {
            short8 ah[4], al[4], bh[4], bl[4];
            #pragma unroll
            for (int mf = 0; mf < 4; ++mf) {
                int off = (wr + mf * 16 + (l & 15)) * 64 + kk + (l >> 4) * 8;
                ah[mf] = *(const short8*)(AsH + off);
                al[mf] = *(const short8*)(AsL + off);
            }
            #pragma unroll
            for (int nf = 0; nf < 4; ++nf) {
                int off = (wc + nf * 16 + (l & 15)) * 64 + kk + (l >> 4) * 8;
                bh[nf] = *(const short8*)(BsH + off);
                bl[nf] = *(const short8*)(BsL + off);
            }
            #pragma unroll
            for (int mf = 0; mf < 4; ++mf)
                #pragma unroll
                for (int nf = 0; nf < 4; ++nf) {
                    acc[mf][nf] = __builtin_amdgcn_mfma_f32_16x16x32_bf16(ah[mf], bh[nf], acc[mf][nf], 0, 0, 0);
                    acc[mf][nf] = __builtin_amdgcn_mfma_f32_16x16x32_bf16(al[mf], bh[nf], acc[mf][nf], 0, 0, 0);
                    acc[mf][nf] = __builtin_amdgcn_mfma_f32_16x16x32_bf16(ah[mf], bl[nf], acc[mf][nf], 0, 0, 0);
                }
        }
        __syncthreads();
    }
    #pragma unroll
    for (int nf = 0; nf < 4; ++nf) {
        int col = n0 + wc + nf * 16 + (l & 15);
        float bv = bias[col];
        #pragma unroll
        for (int mf = 0; mf < 4; ++mf) {
            int mrow = m0 + wr + mf * 16 + (l >> 4) * 4;
            #pragma unroll
            for (int q2 = 0; q2 < 4; ++q2) {
                float v = acc[mf][nf][q2] + bv;
                int m = mrow + q2;
                if (col < 768) {
                    gh[(size_t)m * 768 + col] = v;
                } else {
                    int c2 = col - 768;
                    if (c2 < VCD)
                        out_lem[((size_t)m * LMAXD + s) * VCD + c2] = v;
                }
            }
        }
    }
}

__global__ void zflags_k(int* __restrict__ flags)
{
    if (threadIdx.x < 48) flags[threadIdx.x] = 0;
}

// ============ char-CNN MFMA: conv + bias + relu + max, fused ============
__global__ __launch_bounds__(256)
void conv_k(const ushort* __restrict__ cehi, const ushort* __restrict__ celo,
            const ushort* __restrict__ wre, const float* __restrict__ conv_b,
            float* __restrict__ enc_in)
{
    __shared__ __align__(16) ushort Bs[2 * 64 * 192];
    const int tid = threadIdx.x;
    for (int i = tid; i < 2 * 64 * 192 / 8; i += 256)
        ((uint4*)Bs)[i] = ((const uint4*)wre)[i];
    __syncthreads();
    const int w = tid >> 6, l = tid & 63;
    const int p = l & 15, g = l >> 4;
    const int base = (blockIdx.x * 4 + w) * 8;
    for (int wi = 0; wi < 8; ++wi) {
        int n = base + wi;
        short8 ahi[6], alo[6];
        #pragma unroll
        for (int kt = 0; kt < 6; ++kt) {
            int t = kt >> 1;
            int e0 = (kt & 1) * 32 + g * 8;
            int rl = p + t - 1;
            bool val = (rl >= 0 && rl < 16);
            size_t off = (size_t)(n * 16 + rl) * 64 + e0;
            short8 z = (short8){0,0,0,0,0,0,0,0};
            ahi[kt] = val ? *(const short8*)(cehi + off) : z;
            alo[kt] = val ? *(const short8*)(celo + off) : z;
        }
        f4 acc[4];
        #pragma unroll
        for (int nf = 0; nf < 4; ++nf) acc[nf] = (f4){0.f,0.f,0.f,0.f};
        #pragma unroll
        for (int kt = 0; kt < 6; ++kt) {
            #pragma unroll
            for (int nf = 0; nf < 4; ++nf) {
                int boff = (nf * 16 + (l & 15)) * 192 + kt * 32 + g * 8;
                short8 bh = *(const short8*)(Bs + boff);
                short8 bl = *(const short8*)(Bs + 12288 + boff);
                acc[nf] = __builtin_amdgcn_mfma_f32_16x16x32_bf16(ahi[kt], bh, acc[nf], 0, 0, 0);
                acc[nf] = __builtin_amdgcn_mfma_f32_16x16x32_bf16(alo[kt], bh, acc[nf], 0, 0, 0);
                acc[nf] = __builtin_amdgcn_mfma_f32_16x16x32_bf16(ahi[kt], bl, acc[nf], 0, 0, 0);
            }
        }
        #pragma unroll
        for (int nf = 0; nf < 4; ++nf) {
            float m = fmaxf(fmaxf(acc[nf][0], acc[nf][1]), fmaxf(acc[nf][2], acc[nf][3]));
            m = fmaxf(m, __shfl_xor(m, 16));
            m = fmaxf(m, __shfl_xor(m, 32));
            if (l < 16) {
                int c = nf * 16 + l;
                enc_in[(size_t)n * DIN + 128 + c] = fmaxf(0.0f, m + conv_b[c]);
            }
        }
    }
}

// ============ prep kernels ============
__global__ void repack192_k(const float* __restrict__ w, __hip_bfloat16* __restrict__ wre)
{
    int idx = blockIdx.x * 256 + threadIdx.x;
    if (idx >= 64 * 192) return;
    int kk = idx % 192, c = idx / 192;
    int t = kk >> 6, e = kk & 63;
    float v = (e < 48) ? w[(c * 48 + e) * 3 + t] : 0.0f;
    __hip_bfloat16 hi = __float2bfloat16(v);
    wre[idx] = hi;
    wre[64 * 192 + idx] = __float2bfloat16(v - __bfloat162float(hi));
}

__global__ void ce64_k(const int* __restrict__ char_ids, const float* __restrict__ char_emb,
                       __hip_bfloat16* __restrict__ hi, __hip_bfloat16* __restrict__ lo)
{
    size_t idx = (size_t)blockIdx.x * 256 + threadIdx.x;
    if (idx >= (size_t)NROWS * CLW * 64) return;
    int e = idx & 63;
    size_t r = idx >> 6;
    float v = (e < 48) ? char_emb[(size_t)char_ids[r] * CEw + e] : 0.0f;
    __hip_bfloat16 h = __float2bfloat16(v);
    hi[idx] = h;
    lo[idx] = __float2bfloat16(v - __bfloat162float(h));
}

__global__ void wv_k(const int* __restrict__ wid, const float* __restrict__ wemb,
                     float* __restrict__ enc_in)
{
    size_t idx = (size_t)blockIdx.x * 256 + threadIdx.x;
    if (idx >= (size_t)NROWS * 128) return;
    int e = idx & 127; size_t n = idx >> 7;
    enc_in[n * DIN + e] = wemb[(size_t)wid[n] * 128 + e];
}

__global__ void eisplit_k(const float* __restrict__ x, __hip_bfloat16* __restrict__ hi,
                          __hip_bfloat16* __restrict__ lo)
{
    size_t idx = (size_t)blockIdx.x * 256 + threadIdx.x;
    if (idx >= (size_t)NROWS * DIN) return;
    float v = x[idx];
    __hip_bfloat16 h = __float2bfloat16(v);
    hi[idx] = h;
    lo[idx] = __float2bfloat16(v - __bfloat162float(h));
}

__global__ void wsplit_k(const float* __restrict__ W, __hip_bfloat16* __restrict__ out,
                         int rows, int rowsPad, int K)
{
    int idx = blockIdx.x * 256 + threadIdx.x;
    if (idx >= rowsPad * K) return;
    int r = idx / K, k = idx - r * K;
    float v = (r < rows) ? W[(size_t)r * K + k] : 0.0f;
    __hip_bfloat16 hi = __float2bfloat16(v);
    out[idx] = hi;
    out[rowsPad * K + idx] = __float2bfloat16(v - __bfloat162float(hi));
}

// combined decode B: rows 0..767 = gru_whh, 768..967 = proj_w, 968..1023 = 0; + combined bias
__global__ void cmbsplit_k(const float* __restrict__ whh, const float* __restrict__ proj,
                           const float* __restrict__ bhh, const float* __restrict__ pb,
                           __hip_bfloat16* __restrict__ out, float* __restrict__ cbias)
{
    int idx = blockIdx.x * 256 + threadIdx.x;
    if (idx >= 1024 * 256) return;
    int r = idx >> 8, k = idx & 255;
    float v = (r < 768) ? whh[(size_t)r * 256 + k] : ((r < 968) ? proj[(size_t)(r - 768) * 256 + k] : 0.0f);
    __hip_bfloat16 hi = __float2bfloat16(v);
    out[idx] = hi;
    out[1024 * 256 + idx] = __float2bfloat16(v - __bfloat162float(hi));
    if (idx < 1024)
        cbias[idx] = (idx < 768) ? bhh[idx] : ((idx < 968) ? pb[idx - 768] : 0.0f);
}

// whhT4[dir][k][j][gate] f32, gates (i,f,g,o)
__global__ void whht_k(const float* __restrict__ fw, const float* __restrict__ bw,
                       float* __restrict__ out)
{
    int idx = blockIdx.x * 256 + threadIdx.x;
    if (idx >= 131072) return;
    int q = idx & 3, j = (idx >> 2) & 127, k = (idx >> 9) & 127, d = idx >> 16;
    const float* w = d ? bw : fw;
    out[idx] = w[(size_t)(q * 128 + j) * 128 + k];
}

__global__ void gitab_k(const float* __restrict__ lemb, const float* __restrict__ wih,
                        const float* __restrict__ bih, float* __restrict__ git)
{
    int idx = blockIdx.x * 256 + threadIdx.x;
    if (idx >= VCD * 768) return;
    int g = idx % 768, v = idx / 768;
    float s = bih[g];
    #pragma unroll
    for (int k = 0; k < CEw; ++k) s = fmaf(lemb[v * CEw + k], wih[(size_t)g * CEw + k], s);
    git[idx] = s;
}

// ============ BiLSTM recurrence (gi prefetch; enc written as bf16 hi/lo planes) ============
__global__ __launch_bounds__(1024, 4)
void lstm_k(const float* __restrict__ gi2, const float* __restrict__ whht,
            __hip_bfloat16* __restrict__ enc_hi, __hip_bfloat16* __restrict__ enc_lo)
{
    const int dir = blockIdx.x >> 6, b = blockIdx.x & 63;
    const int tid = threadIdx.x;
    const int j = tid & 127, q = tid >> 7;
    const float* gi = gi2 + (size_t)dir * NROWS * 512;
    const f4* wt = (const f4*)(whht + (size_t)dir * 65536);
    f4 wreg[16];
    #pragma unroll
    for (int kk = 0; kk < 16; ++kk) wreg[kk] = wt[(q * 16 + kk) * 128 + j];
    __shared__ float hbuf[128];
    __shared__ f4 part[8][128];
    float c = 0.0f;
    if (tid < 128) hbuf[tid] = 0.0f;
    float nai = 0.f, naf = 0.f, nag = 0.f, nao = 0.f;
    if (q == 0) {
        int t0 = dir ? (TSEQ - 1) : 0;
        const float* gr = gi + ((size_t)b * TSEQ + t0) * 512;
        nai = gr[j]; naf = gr[128 + j]; nag = gr[256 + j]; nao = gr[384 + j];
    }
    __syncthreads();
    for (int s = 0; s < TSEQ; ++s) {
        int t = dir ? (TSEQ - 1 - s) : s;
        size_t n = (size_t)b * TSEQ + t;
        float ai = nai, af = naf, ag = nag, ao = nao;
        const f4* hb = (const f4*)(hbuf + q * 16);
        f4 hh[4] = {hb[0], hb[1], hb[2], hb[3]};
        f4 p = (f4){0.f,0.f,0.f,0.f};
        #pragma unroll
        for (int kk = 0; kk < 16; ++kk) {
            float hv = hh[kk >> 2][kk & 3];
            p.x = fmaf(wreg[kk].x, hv, p.x);
            p.y = fmaf(wreg[kk].y, hv, p.y);
            p.z = fmaf(wreg[kk].z, hv, p.z);
            p.w = fmaf(wreg[kk].w, hv, p.w);
        }
        part[q][j] = p;
        __syncthreads();
        if (q == 0) {
            f4 sum = part[0][j];
            #pragma unroll
            for (int qq = 1; qq < 8; ++qq) {
                f4 pp = part[qq][j];
                sum.x += pp.x; sum.y += pp.y; sum.z += pp.z; sum.w += pp.w;
            }
            ai += sum.x; af += sum.y; ag += sum.z; ao += sum.w;
            c = sigf(af) * c + sigf(ai) * tanhf(ag);
            float h = sigf(ao) * tanhf(c);
            hbuf[j] = h;
            size_t o = n * HH + dir * 128 + j;
            __hip_bfloat16 hi = __float2bfloat16(h);
            enc_hi[o] = hi;
            enc_lo[o] = __float2bfloat16(h - __bfloat162float(hi));
            if (s + 1 < TSEQ) {
                int t2 = dir ? (TSEQ - 2 - s) : (s + 1);
                const float* gr2 = gi + ((size_t)b * TSEQ + t2) * 512;
                nai = gr2[j]; naf = gr2[128 + j]; nag = gr2[256 + j]; nao = gr2[384 + j];
            }
        }
        __syncthreads();
    }
}

extern "C" void kernel_launch(void* const* d_in, const int* in_sizes, int n_in,
                              void* d_out, int out_size, void* d_ws, size_t ws_size,
                              hipStream_t stream)
{
    const int*   word_ids = (const int*)d_in[0];
    const int*   char_ids = (const int*)d_in[1];
    const float* word_emb = (const float*)d_in[2];
    const float* char_emb = (const float*)d_in[3];
    const float* conv_w   = (const float*)d_in[4];
    const float* conv_b   = (const float*)d_in[5];
    const float* fw_wih   = (const float*)d_in[6];
    const float* fw_whh   = (const float*)d_in[7];
    const float* fw_b     = (const float*)d_in[8];
    const float* bw_wih   = (const float*)d_in[9];
    const float* bw_whh   = (const float*)d_in[10];
    const float* bw_b     = (const float*)d_in[11];
    const float* tag_w    = (const float*)d_in[12];
    const float* tag_b    = (const float*)d_in[13];
    const float* lemma_emb= (const float*)d_in[14];
    const float* init_w   = (const float*)d_in[15];
    const float* init_b   = (const float*)d_in[16];
    const float* gru_wih  = (const float*)d_in[17];
    const float* gru_whh  = (const float*)d_in[18];
    const float* gru_bih  = (const float*)d_in[19];
    const float* gru_bhh  = (const float*)d_in[20];
    const float* proj_b   = (const float*)d_in[22];
    const float* proj_w   = (const float*)d_in[21];

    // ---- workspace (lifetime-aliased) ----
    char* ws = (char*)d_ws;
    float* enc_in = (float*)(ws);                                  // [6144,192] f32 (front-end)
    __hip_bfloat16* ei_hi = (__hip_bfloat16*)(ws + 4718592);       // [6144,192]
    __hip_bfloat16* ei_lo = (__hip_bfloat16*)(ws + 7077888);       // [6144,192]
    __hip_bfloat16* enc_hi = (__hip_bfloat16*)(ws);                // [6144,256] (phase2)
    __hip_bfloat16* enc_lo = (__hip_bfloat16*)(ws + 3145728);      // [6144,256] (phase2)
    char* R1 = ws + 9437184;                                       // 25.17 MB region
    __hip_bfloat16* ce_hi = (__hip_bfloat16*)R1;                   // [98304,64]
    __hip_bfloat16* ce_lo = (__hip_bfloat16*)(R1 + 12582912);      // [98304,64]
    float* gi2 = (float*)R1;                                       // [2,6144,512]
    float* gh  = (float*)R1;                                       // [6144,768] (decode)
    __hip_bfloat16* cmb_ext = (__hip_bfloat16*)(R1 + 18874368);    // [2][1024][256] (decode)
    float* cmb_bias = (float*)(R1 + 18874368 + 1048576);           // [1024]
    float* hdec = (float*)(ws + 34603008);                         // [6144,256] (init C out)
    __hip_bfloat16* h_hi = (__hip_bfloat16*)(ws + 40894464);       // [6144,256]
    __hip_bfloat16* h_lo = (__hip_bfloat16*)(ws + 44040192);       // [6144,256]
    float* git  = (float*)(ws + 47185920);                         // [200,768]
    float* whht = (float*)(ws + 47800320);                         // [2,128,128,4]
    int*   flags = (int*)(ws + 48324608);                          // [48]
    __hip_bfloat16* wre_ext  = (__hip_bfloat16*)(ws + 48349184);   // [2][64][192]
    __hip_bfloat16* wfw_ext  = (__hip_bfloat16*)(ws + 48398336);   // [2][512][192]
    __hip_bfloat16* wbw_ext  = (__hip_bfloat16*)(ws + 48791552);   // [2][512][192]
    __hip_bfloat16* tag_ext  = (__hip_bfloat16*)(ws + 49184768);   // [2][640][256]
    __hip_bfloat16* init_ext = (__hip_bfloat16*)(ws + 49840128);   // [2][256][256]

    float* out_tag = (float*)d_out;                                // [6144,600]
    float* out_lem = out_tag + (size_t)NROWS * NTAGS;              // [6144,24,200]

    // ---- front-end ----
    repack192_k<<<48, 256, 0, stream>>>(conv_w, wre_ext);
    ce64_k<<<24576, 256, 0, stream>>>(char_ids, char_emb, ce_hi, ce_lo);
    wv_k<<<3072, 256, 0, stream>>>(word_ids, word_emb, enc_in);
    conv_k<<<192, 256, 0, stream>>>((const ushort*)ce_hi, (const ushort*)ce_lo,
                                    (const ushort*)wre_ext, conv_b, enc_in);
    eisplit_k<<<4608, 256, 0, stream>>>(enc_in, ei_hi, ei_lo);
    wsplit_k<<<384, 256, 0, stream>>>(fw_wih, wfw_ext, 512, 512, 192);
    wsplit_k<<<384, 256, 0, stream>>>(bw_wih, wbw_ext, 512, 512, 192);

    // ---- LSTM input gates (MFMA), then recurrence ----
    gemm3_k<0,0,192><<<dim3(48,4), 256, 0, stream>>>((const ushort*)ei_hi, (const ushort*)ei_lo,
        (const ushort*)wfw_ext, (const ushort*)(wfw_ext + 512*192), fw_b, gi2,
        nullptr, nullptr, 512, 512);
    gemm3_k<0,0,192><<<dim3(48,4), 256, 0, stream>>>((const ushort*)ei_hi, (const ushort*)ei_lo,
        (const ushort*)wbw_ext, (const ushort*)(wbw_ext + 512*192), bw_b, gi2 + (size_t)NROWS*512,
        nullptr, nullptr, 512, 512);
    whht_k<<<512, 256, 0, stream>>>(fw_whh, bw_whh, whht);
    lstm_k<<<128, 1024, 0, stream>>>(gi2, whht, enc_hi, enc_lo);

    // ---- heads (MFMA) + decode prep ----
    cmbsplit_k<<<1024, 256, 0, stream>>>(gru_whh, proj_w, gru_bhh, proj_b, cmb_ext, cmb_bias);
    wsplit_k<<<640, 256, 0, stream>>>(tag_w, tag_ext, 600, 640, 256);
    wsplit_k<<<256, 256, 0, stream>>>(init_w, init_ext, 256, 256, 256);
    gitab_k<<<600, 256, 0, stream>>>(lemma_emb, gru_wih, gru_bih, git);
    zflags_k<<<1, 64, 0, stream>>>(flags);
    gemm3_k<0,0,256><<<dim3(48,5), 256, 0, stream>>>((const ushort*)enc_hi, (const ushort*)enc_lo,
        (const ushort*)tag_ext, (const ushort*)(tag_ext + 640*256), tag_b, out_tag,
        nullptr, nullptr, NTAGS, NTAGS);
    gemm3_k<1,1,256><<<dim3(48,2), 256, 0, stream>>>((const ushort*)enc_hi, (const ushort*)enc_lo,
        (const ushort*)init_ext, (const ushort*)(init_ext + 256*256), init_b, hdec,
        (ushort*)h_hi, (ushort*)h_lo, 256, 256);

    // ---- greedy GRU decode: priming gh_0, then 24 fused steps ----
    const ushort* cmb_hi = (const ushort*)cmb_ext;
    const ushort* cmb_lo = cmb_hi + 1024 * 256;
    gemmC_k<<<dim3(48,6), 256, 0, stream>>>((const ushort*)h_hi, (const ushort*)h_lo,
        cmb_hi, cmb_lo, cmb_bias, gh);
    for (int s = 0; s < LMAXD; ++s) {
        dec_k<<<dim3(48,8), 256, 0, stream>>>(gh, git, out_lem,
            (ushort*)h_hi, (ushort*)h_lo, cmb_hi, cmb_lo, cmb_bias, flags, s);
    }
}

// Round 11
// 898.602 us; speedup vs baseline: 5.6586x; 5.6586x over previous
//
#include <hip/hip_runtime.h>
#include <hip/hip_bf16.h>
#include <math.h>

typedef float f4 __attribute__((ext_vector_type(4)));
typedef __attribute__((ext_vector_type(8))) short short8;

#define NTAGS 600
#define CEw   48
#define HH    256
#define TSEQ  96
#define CLW   16
#define LMAXD 24
#define NROWS 6144
#define DIN   192
#define VCD   200

__device__ __forceinline__ float sigf(float x){ return 1.0f/(1.0f+expf(-x)); }
__device__ __forceinline__ ushort bhi_u(float v){ __hip_bfloat16 h = __float2bfloat16(v); return *(ushort*)&h; }
__device__ __forceinline__ float ub_f(ushort u){ __hip_bfloat16 h = *(__hip_bfloat16*)&u; return __bfloat162float(h); }

// ============ generalized MFMA 3-term GEMM (per-segment staging; proven) ============
template<int ACT, int HS, int KK>
__global__ __launch_bounds__(256)
void gemm3_k(const ushort* __restrict__ Ahi, const ushort* __restrict__ Alo,
             const ushort* __restrict__ Bhi, const ushort* __restrict__ Blo,
             const float* __restrict__ bias, float* __restrict__ C,
             ushort* __restrict__ Hhi, ushort* __restrict__ Hlo,
             int Nc, int ldC)
{
    __shared__ __align__(16) ushort As[128 * 64];
    __shared__ __align__(16) ushort Bs[128 * 64];
    const int tid = threadIdx.x;
    const int m0 = blockIdx.x * 128;
    const int n0 = blockIdx.y * 128;
    const int w = tid >> 6, l = tid & 63;
    const int wr = (w >> 1) * 64, wc = (w & 1) * 64;
    f4 acc[4][4];
    #pragma unroll
    for (int i = 0; i < 4; ++i)
        #pragma unroll
        for (int j = 0; j < 4; ++j) acc[i][j] = (f4){0.f,0.f,0.f,0.f};

    #pragma unroll
    for (int seg = 0; seg < 3; ++seg) {
        const ushort* Ap = (seg == 1) ? Alo : Ahi;
        const ushort* Bp = (seg == 2) ? Blo : Bhi;
        #pragma unroll
        for (int kt = 0; kt < KK; kt += 64) {
            #pragma unroll
            for (int i = 0; i < 4; ++i) {
                int c = w * 4 + i;
                int row = c * 8 + (l >> 3);
                int col16 = l & 7;
                __builtin_amdgcn_global_load_lds(
                    (const __attribute__((address_space(1))) void*)(Ap + (size_t)(m0 + row) * KK + kt + col16 * 8),
                    (__attribute__((address_space(3))) void*)((char*)As + c * 1024 + l * 16), 16, 0, 0);
                __builtin_amdgcn_global_load_lds(
                    (const __attribute__((address_space(1))) void*)(Bp + (size_t)(n0 + row) * KK + kt + col16 * 8),
                    (__attribute__((address_space(3))) void*)((char*)Bs + c * 1024 + l * 16), 16, 0, 0);
            }
            __syncthreads();
            #pragma unroll
            for (int kk = 0; kk < 64; kk += 32) {
                short8 a[4], b[4];
                #pragma unroll
                for (int mf = 0; mf < 4; ++mf)
                    a[mf] = *(const short8*)(As + (wr + mf * 16 + (l & 15)) * 64 + kk + (l >> 4) * 8);
                #pragma unroll
                for (int nf = 0; nf < 4; ++nf)
                    b[nf] = *(const short8*)(Bs + (wc + nf * 16 + (l & 15)) * 64 + kk + (l >> 4) * 8);
                #pragma unroll
                for (int mf = 0; mf < 4; ++mf)
                    #pragma unroll
                    for (int nf = 0; nf < 4; ++nf)
                        acc[mf][nf] = __builtin_amdgcn_mfma_f32_16x16x32_bf16(a[mf], b[nf], acc[mf][nf], 0, 0, 0);
            }
            __syncthreads();
        }
    }
    #pragma unroll
    for (int nf = 0; nf < 4; ++nf) {
        int n = n0 + wc + nf * 16 + (l & 15);
        if (n >= Nc) continue;
        float bv = bias[n];
        #pragma unroll
        for (int mf = 0; mf < 4; ++mf) {
            int mrow = m0 + wr + mf * 16 + (l >> 4) * 4;
            #pragma unroll
            for (int q2 = 0; q2 < 4; ++q2) {
                float v = acc[mf][nf][q2] + bv;
                if (ACT == 1) v = tanhf(v);
                size_t o = (size_t)(mrow + q2) * ldC + n;
                C[o] = v;
                if (HS) {
                    ushort hi = bhi_u(v);
                    Hhi[o] = hi;
                    Hlo[o] = bhi_u(v - ub_f(hi));
                }
            }
        }
    }
}

// ============ decode GEMM, 64x128 tile (3 blocks/CU, one-round grid 96x8) ============
// C = h @ [whh | proj]^T; cols<768 -> gh; cols in [768,968) -> lem (if non-null).
__global__ __launch_bounds__(256)
void gemmC_k(const ushort* __restrict__ Ahi, const ushort* __restrict__ Alo,
             const ushort* __restrict__ Bhi, const ushort* __restrict__ Blo,
             const float* __restrict__ bias,
             float* __restrict__ gh, float* __restrict__ lem)
{
    __shared__ __align__(16) ushort AsH[64 * 64];
    __shared__ __align__(16) ushort AsL[64 * 64];
    __shared__ __align__(16) ushort BsH[128 * 64];
    __shared__ __align__(16) ushort BsL[128 * 64];
    const int tid = threadIdx.x;
    const int m0 = blockIdx.x * 64;
    const int n0 = blockIdx.y * 128;
    const int w = tid >> 6, l = tid & 63;
    const int wr = (w >> 1) * 32, wc = (w & 1) * 64;
    f4 acc[2][4];
    #pragma unroll
    for (int i = 0; i < 2; ++i)
        #pragma unroll
        for (int j = 0; j < 4; ++j) acc[i][j] = (f4){0.f,0.f,0.f,0.f};

    #pragma unroll
    for (int kt = 0; kt < 256; kt += 64) {
        const int col16 = l & 7;
        #pragma unroll
        for (int i = 0; i < 2; ++i) {                 // A: 8 chunks, 2/wave
            int c = w * 2 + i;
            int row = c * 8 + (l >> 3);
            size_t ga = (size_t)(m0 + row) * 256 + kt + col16 * 8;
            int loff = c * 1024 + l * 16;
            __builtin_amdgcn_global_load_lds(
                (const __attribute__((address_space(1))) void*)(Ahi + ga),
                (__attribute__((address_space(3))) void*)((char*)AsH + loff), 16, 0, 0);
            __builtin_amdgcn_global_load_lds(
                (const __attribute__((address_space(1))) void*)(Alo + ga),
                (__attribute__((address_space(3))) void*)((char*)AsL + loff), 16, 0, 0);
        }
        #pragma unroll
        for (int i = 0; i < 4; ++i) {                 // B: 16 chunks, 4/wave
            int c = w * 4 + i;
            int row = c * 8 + (l >> 3);
            size_t gb = (size_t)(n0 + row) * 256 + kt + col16 * 8;
            int loff = c * 1024 + l * 16;
            __builtin_amdgcn_global_load_lds(
                (const __attribute__((address_space(1))) void*)(Bhi + gb),
                (__attribute__((address_space(3))) void*)((char*)BsH + loff), 16, 0, 0);
            __builtin_amdgcn_global_load_lds(
                (const __attribute__((address_space(1))) void*)(Blo + gb),
                (__attribute__((address_space(3))) void*)((char*)BsL + loff), 16, 0, 0);
        }
        __syncthreads();
        #pragma unroll
        for (int kk = 0; kk < 64; kk += 32) {
            short8 ah[2], al[2], bh[4], bl[4];
            #pragma unroll
            for (int mf = 0; mf < 2; ++mf) {
                int off = (wr + mf * 16 + (l & 15)) * 64 + kk + (l >> 4) * 8;
                ah[mf] = *(const short8*)(AsH + off);
                al[mf] = *(const short8*)(AsL + off);
            }
            #pragma unroll
            for (int nf = 0; nf < 4; ++nf) {
                int off = (wc + nf * 16 + (l & 15)) * 64 + kk + (l >> 4) * 8;
                bh[nf] = *(const short8*)(BsH + off);
                bl[nf] = *(const short8*)(BsL + off);
            }
            #pragma unroll
            for (int mf = 0; mf < 2; ++mf)
                #pragma unroll
                for (int nf = 0; nf < 4; ++nf) {
                    acc[mf][nf] = __builtin_amdgcn_mfma_f32_16x16x32_bf16(ah[mf], bh[nf], acc[mf][nf], 0, 0, 0);
                    acc[mf][nf] = __builtin_amdgcn_mfma_f32_16x16x32_bf16(al[mf], bh[nf], acc[mf][nf], 0, 0, 0);
                    acc[mf][nf] = __builtin_amdgcn_mfma_f32_16x16x32_bf16(ah[mf], bl[nf], acc[mf][nf], 0, 0, 0);
                }
        }
        __syncthreads();
    }
    #pragma unroll
    for (int nf = 0; nf < 4; ++nf) {
        int col = n0 + wc + nf * 16 + (l & 15);
        float bv = bias[col];
        #pragma unroll
        for (int mf = 0; mf < 2; ++mf) {
            int mrow = m0 + wr + mf * 16 + (l >> 4) * 4;
            #pragma unroll
            for (int q2 = 0; q2 < 4; ++q2) {
                float v = acc[mf][nf][q2] + bv;
                int m = mrow + q2;
                if (col < 768) {
                    gh[(size_t)m * 768 + col] = v;
                } else {
                    int c2 = col - 768;
                    if (c2 < VCD && lem)
                        lem[(size_t)m * (LMAXD * VCD) + c2] = v;
                }
            }
        }
    }
}

// ============ fused argmax(prev logits) + GRU pointwise update ============
__global__ __launch_bounds__(256)
void argupd_k(const float* __restrict__ gh, const float* __restrict__ git,
              const float* __restrict__ lem, float* __restrict__ h,
              ushort* __restrict__ hhi, ushort* __restrict__ hlo)
{
    const int n = blockIdx.x, tid = threadIdx.x;
    __shared__ float sv[4];
    __shared__ int   si[4];
    __shared__ int   sprev;
    if (lem) {
        float v = (tid < VCD) ? lem[(size_t)n * (LMAXD * VCD) + tid] : -3.4e38f;
        int bi = tid;
        #pragma unroll
        for (int d = 1; d < 64; d <<= 1) {
            float ov = __shfl_xor(v, d);
            int   oi = __shfl_xor(bi, d);
            if (ov > v || (ov == v && oi < bi)) { v = ov; bi = oi; }
        }
        if ((tid & 63) == 0) { sv[tid >> 6] = v; si[tid >> 6] = bi; }
        __syncthreads();
        if (tid == 0) {
            float b = sv[0]; int bi2 = si[0];
            #pragma unroll
            for (int t2 = 1; t2 < 4; ++t2)
                if (sv[t2] > b || (sv[t2] == b && si[t2] < bi2)) { b = sv[t2]; bi2 = si[t2]; }
            sprev = bi2;
        }
    } else if (tid == 0) sprev = 3;   // BOS
    __syncthreads();
    const int prev = sprev;
    const int j = tid;
    const float* g  = gh + (size_t)n * 768;
    const float* gi = git + (size_t)prev * 768;
    float r  = sigf(gi[j] + g[j]);
    float z  = sigf(gi[256 + j] + g[256 + j]);
    float nn = tanhf(gi[512 + j] + r * g[512 + j]);
    size_t o = (size_t)n * HH + j;
    float hv = (1.0f - z) * nn + z * h[o];
    h[o] = hv;
    ushort hi = bhi_u(hv);
    hhi[o] = hi;
    hlo[o] = bhi_u(hv - ub_f(hi));
}

// ============ char-CNN MFMA: conv + bias + relu + max, fused ============
__global__ __launch_bounds__(256)
void conv_k(const ushort* __restrict__ cehi, const ushort* __restrict__ celo,
            const ushort* __restrict__ wre, const float* __restrict__ conv_b,
            float* __restrict__ enc_in)
{
    __shared__ __align__(16) ushort Bs[2 * 64 * 192];
    const int tid = threadIdx.x;
    for (int i = tid; i < 2 * 64 * 192 / 8; i += 256)
        ((uint4*)Bs)[i] = ((const uint4*)wre)[i];
    __syncthreads();
    const int w = tid >> 6, l = tid & 63;
    const int p = l & 15, g = l >> 4;
    const int base = (blockIdx.x * 4 + w) * 8;
    for (int wi = 0; wi < 8; ++wi) {
        int n = base + wi;
        short8 ahi[6], alo[6];
        #pragma unroll
        for (int kt = 0; kt < 6; ++kt) {
            int t = kt >> 1;
            int e0 = (kt & 1) * 32 + g * 8;
            int rl = p + t - 1;
            bool val = (rl >= 0 && rl < 16);
            size_t off = (size_t)(n * 16 + rl) * 64 + e0;
            short8 z = (short8){0,0,0,0,0,0,0,0};
            ahi[kt] = val ? *(const short8*)(cehi + off) : z;
            alo[kt] = val ? *(const short8*)(celo + off) : z;
        }
        f4 acc[4];
        #pragma unroll
        for (int nf = 0; nf < 4; ++nf) acc[nf] = (f4){0.f,0.f,0.f,0.f};
        #pragma unroll
        for (int kt = 0; kt < 6; ++kt) {
            #pragma unroll
            for (int nf = 0; nf < 4; ++nf) {
                int boff = (nf * 16 + (l & 15)) * 192 + kt * 32 + g * 8;
                short8 bh = *(const short8*)(Bs + boff);
                short8 bl = *(const short8*)(Bs + 12288 + boff);
                acc[nf] = __builtin_amdgcn_mfma_f32_16x16x32_bf16(ahi[kt], bh, acc[nf], 0, 0, 0);
                acc[nf] = __builtin_amdgcn_mfma_f32_16x16x32_bf16(alo[kt], bh, acc[nf], 0, 0, 0);
                acc[nf] = __builtin_amdgcn_mfma_f32_16x16x32_bf16(ahi[kt], bl, acc[nf], 0, 0, 0);
            }
        }
        #pragma unroll
        for (int nf = 0; nf < 4; ++nf) {
            float m = fmaxf(fmaxf(acc[nf][0], acc[nf][1]), fmaxf(acc[nf][2], acc[nf][3]));
            m = fmaxf(m, __shfl_xor(m, 16));
            m = fmaxf(m, __shfl_xor(m, 32));
            if (l < 16) {
                int c = nf * 16 + l;
                enc_in[(size_t)n * DIN + 128 + c] = fmaxf(0.0f, m + conv_b[c]);
            }
        }
    }
}

// ============ prep kernels ============
__global__ void repack192_k(const float* __restrict__ w, __hip_bfloat16* __restrict__ wre)
{
    int idx = blockIdx.x * 256 + threadIdx.x;
    if (idx >= 64 * 192) return;
    int kk = idx % 192, c = idx / 192;
    int t = kk >> 6, e = kk & 63;
    float v = (e < 48) ? w[(c * 48 + e) * 3 + t] : 0.0f;
    __hip_bfloat16 hi = __float2bfloat16(v);
    wre[idx] = hi;
    wre[64 * 192 + idx] = __float2bfloat16(v - __bfloat162float(hi));
}

__global__ void ce64_k(const int* __restrict__ char_ids, const float* __restrict__ char_emb,
                       __hip_bfloat16* __restrict__ hi, __hip_bfloat16* __restrict__ lo)
{
    size_t idx = (size_t)blockIdx.x * 256 + threadIdx.x;
    if (idx >= (size_t)NROWS * CLW * 64) return;
    int e = idx & 63;
    size_t r = idx >> 6;
    float v = (e < 48) ? char_emb[(size_t)char_ids[r] * CEw + e] : 0.0f;
    __hip_bfloat16 h = __float2bfloat16(v);
    hi[idx] = h;
    lo[idx] = __float2bfloat16(v - __bfloat162float(h));
}

__global__ void wv_k(const int* __restrict__ wid, const float* __restrict__ wemb,
                     float* __restrict__ enc_in)
{
    size_t idx = (size_t)blockIdx.x * 256 + threadIdx.x;
    if (idx >= (size_t)NROWS * 128) return;
    int e = idx & 127; size_t n = idx >> 7;
    enc_in[n * DIN + e] = wemb[(size_t)wid[n] * 128 + e];
}

__global__ void eisplit_k(const float* __restrict__ x, __hip_bfloat16* __restrict__ hi,
                          __hip_bfloat16* __restrict__ lo)
{
    size_t idx = (size_t)blockIdx.x * 256 + threadIdx.x;
    if (idx >= (size_t)NROWS * DIN) return;
    float v = x[idx];
    __hip_bfloat16 h = __float2bfloat16(v);
    hi[idx] = h;
    lo[idx] = __float2bfloat16(v - __bfloat162float(h));
}

__global__ void wsplit_k(const float* __restrict__ W, __hip_bfloat16* __restrict__ out,
                         int rows, int rowsPad, int K)
{
    int idx = blockIdx.x * 256 + threadIdx.x;
    if (idx >= rowsPad * K) return;
    int r = idx / K, k = idx - r * K;
    float v = (r < rows) ? W[(size_t)r * K + k] : 0.0f;
    __hip_bfloat16 hi = __float2bfloat16(v);
    out[idx] = hi;
    out[rowsPad * K + idx] = __float2bfloat16(v - __bfloat162float(hi));
}

// combined decode B: rows 0..767 = gru_whh, 768..967 = proj_w, 968..1023 = 0; + combined bias
__global__ void cmbsplit_k(const float* __restrict__ whh, const float* __restrict__ proj,
                           const float* __restrict__ bhh, const float* __restrict__ pb,
                           __hip_bfloat16* __restrict__ out, float* __restrict__ cbias)
{
    int idx = blockIdx.x * 256 + threadIdx.x;
    if (idx >= 1024 * 256) return;
    int r = idx >> 8, k = idx & 255;
    float v = (r < 768) ? whh[(size_t)r * 256 + k] : ((r < 968) ? proj[(size_t)(r - 768) * 256 + k] : 0.0f);
    __hip_bfloat16 hi = __float2bfloat16(v);
    out[idx] = hi;
    out[1024 * 256 + idx] = __float2bfloat16(v - __bfloat162float(hi));
    if (idx < 1024)
        cbias[idx] = (idx < 768) ? bhh[idx] : ((idx < 968) ? pb[idx - 768] : 0.0f);
}

// whhT4[dir][k][j][gate] f32, gates (i,f,g,o)
__global__ void whht_k(const float* __restrict__ fw, const float* __restrict__ bw,
                       float* __restrict__ out)
{
    int idx = blockIdx.x * 256 + threadIdx.x;
    if (idx >= 131072) return;
    int q = idx & 3, j = (idx >> 2) & 127, k = (idx >> 9) & 127, d = idx >> 16;
    const float* w = d ? bw : fw;
    out[idx] = w[(size_t)(q * 128 + j) * 128 + k];
}

__global__ void gitab_k(const float* __restrict__ lemb, const float* __restrict__ wih,
                        const float* __restrict__ bih, float* __restrict__ git)
{
    int idx = blockIdx.x * 256 + threadIdx.x;
    if (idx >= VCD * 768) return;
    int g = idx % 768, v = idx / 768;
    float s = bih[g];
    #pragma unroll
    for (int k = 0; k < CEw; ++k) s = fmaf(lemb[v * CEw + k], wih[(size_t)g * CEw + k], s);
    git[idx] = s;
}

// ============ BiLSTM recurrence (gi prefetch; enc written as bf16 hi/lo planes) ============
__global__ __launch_bounds__(1024, 4)
void lstm_k(const float* __restrict__ gi2, const float* __restrict__ whht,
            __hip_bfloat16* __restrict__ enc_hi, __hip_bfloat16* __restrict__ enc_lo)
{
    const int dir = blockIdx.x >> 6, b = blockIdx.x & 63;
    const int tid = threadIdx.x;
    const int j = tid & 127, q = tid >> 7;
    const float* gi = gi2 + (size_t)dir * NROWS * 512;
    const f4* wt = (const f4*)(whht + (size_t)dir * 65536);
    f4 wreg[16];
    #pragma unroll
    for (int kk = 0; kk < 16; ++kk) wreg[kk] = wt[(q * 16 + kk) * 128 + j];
    __shared__ float hbuf[128];
    __shared__ f4 part[8][128];
    float c = 0.0f;
    if (tid < 128) hbuf[tid] = 0.0f;
    float nai = 0.f, naf = 0.f, nag = 0.f, nao = 0.f;
    if (q == 0) {
        int t0 = dir ? (TSEQ - 1) : 0;
        const float* gr = gi + ((size_t)b * TSEQ + t0) * 512;
        nai = gr[j]; naf = gr[128 + j]; nag = gr[256 + j]; nao = gr[384 + j];
    }
    __syncthreads();
    for (int s = 0; s < TSEQ; ++s) {
        int t = dir ? (TSEQ - 1 - s) : s;
        size_t n = (size_t)b * TSEQ + t;
        float ai = nai, af = naf, ag = nag, ao = nao;
        const f4* hb = (const f4*)(hbuf + q * 16);
        f4 hh[4] = {hb[0], hb[1], hb[2], hb[3]};
        f4 p = (f4){0.f,0.f,0.f,0.f};
        #pragma unroll
        for (int kk = 0; kk < 16; ++kk) {
            float hv = hh[kk >> 2][kk & 3];
            p.x = fmaf(wreg[kk].x, hv, p.x);
            p.y = fmaf(wreg[kk].y, hv, p.y);
            p.z = fmaf(wreg[kk].z, hv, p.z);
            p.w = fmaf(wreg[kk].w, hv, p.w);
        }
        part[q][j] = p;
        __syncthreads();
        if (q == 0) {
            f4 sum = part[0][j];
            #pragma unroll
            for (int qq = 1; qq < 8; ++qq) {
                f4 pp = part[qq][j];
                sum.x += pp.x; sum.y += pp.y; sum.z += pp.z; sum.w += pp.w;
            }
            ai += sum.x; af += sum.y; ag += sum.z; ao += sum.w;
            c = sigf(af) * c + sigf(ai) * tanhf(ag);
            float h = sigf(ao) * tanhf(c);
            hbuf[j] = h;
            size_t o = n * HH + dir * 128 + j;
            __hip_bfloat16 hi = __float2bfloat16(h);
            enc_hi[o] = hi;
            enc_lo[o] = __float2bfloat16(h - __bfloat162float(hi));
            if (s + 1 < TSEQ) {
                int t2 = dir ? (TSEQ - 2 - s) : (s + 1);
                const float* gr2 = gi + ((size_t)b * TSEQ + t2) * 512;
                nai = gr2[j]; naf = gr2[128 + j]; nag = gr2[256 + j]; nao = gr2[384 + j];
            }
        }
        __syncthreads();
    }
}

extern "C" void kernel_launch(void* const* d_in, const int* in_sizes, int n_in,
                              void* d_out, int out_size, void* d_ws, size_t ws_size,
                              hipStream_t stream)
{
    const int*   word_ids = (const int*)d_in[0];
    const int*   char_ids = (const int*)d_in[1];
    const float* word_emb = (const float*)d_in[2];
    const float* char_emb = (const float*)d_in[3];
    const float* conv_w   = (const float*)d_in[4];
    const float* conv_b   = (const float*)d_in[5];
    const float* fw_wih   = (const float*)d_in[6];
    const float* fw_whh   = (const float*)d_in[7];
    const float* fw_b     = (const float*)d_in[8];
    const float* bw_wih   = (const float*)d_in[9];
    const float* bw_whh   = (const float*)d_in[10];
    const float* bw_b     = (const float*)d_in[11];
    const float* tag_w    = (const float*)d_in[12];
    const float* tag_b    = (const float*)d_in[13];
    const float* lemma_emb= (const float*)d_in[14];
    const float* init_w   = (const float*)d_in[15];
    const float* init_b   = (const float*)d_in[16];
    const float* gru_wih  = (const float*)d_in[17];
    const float* gru_whh  = (const float*)d_in[18];
    const float* gru_bih  = (const float*)d_in[19];
    const float* gru_bhh  = (const float*)d_in[20];
    const float* proj_w   = (const float*)d_in[21];
    const float* proj_b   = (const float*)d_in[22];

    // ---- workspace (lifetime-aliased) ----
    char* ws = (char*)d_ws;
    float* enc_in = (float*)(ws);                                  // [6144,192] f32 (front-end)
    __hip_bfloat16* ei_hi = (__hip_bfloat16*)(ws + 4718592);       // [6144,192]
    __hip_bfloat16* ei_lo = (__hip_bfloat16*)(ws + 7077888);       // [6144,192]
    __hip_bfloat16* enc_hi = (__hip_bfloat16*)(ws);                // [6144,256] (phase2)
    __hip_bfloat16* enc_lo = (__hip_bfloat16*)(ws + 3145728);      // [6144,256] (phase2)
    char* R1 = ws + 9437184;                                       // 25.17 MB region
    __hip_bfloat16* ce_hi = (__hip_bfloat16*)R1;                   // [98304,64]
    __hip_bfloat16* ce_lo = (__hip_bfloat16*)(R1 + 12582912);      // [98304,64]
    float* gi2 = (float*)R1;                                       // [2,6144,512]
    float* gh  = (float*)R1;                                       // [6144,768] (decode)
    __hip_bfloat16* cmb_ext = (__hip_bfloat16*)(R1 + 18874368);    // [2][1024][256] (decode)
    float* cmb_bias = (float*)(R1 + 18874368 + 1048576);           // [1024]
    float* hdec = (float*)(ws + 34603008);                         // [6144,256]
    __hip_bfloat16* h_hi = (__hip_bfloat16*)(ws + 40894464);       // [6144,256]
    __hip_bfloat16* h_lo = (__hip_bfloat16*)(ws + 44040192);       // [6144,256]
    float* git  = (float*)(ws + 47185920);                         // [200,768]
    float* whht = (float*)(ws + 47800320);                         // [2,128,128,4]
    __hip_bfloat16* wre_ext  = (__hip_bfloat16*)(ws + 48349184);   // [2][64][192]
    __hip_bfloat16* wfw_ext  = (__hip_bfloat16*)(ws + 48398336);   // [2][512][192]
    __hip_bfloat16* wbw_ext  = (__hip_bfloat16*)(ws + 48791552);   // [2][512][192]
    __hip_bfloat16* tag_ext  = (__hip_bfloat16*)(ws + 49184768);   // [2][640][256]
    __hip_bfloat16* init_ext = (__hip_bfloat16*)(ws + 49840128);   // [2][256][256]

    float* out_tag = (float*)d_out;                                // [6144,600]
    float* out_lem = out_tag + (size_t)NROWS * NTAGS;              // [6144,24,200]

    // ---- front-end ----
    repack192_k<<<48, 256, 0, stream>>>(conv_w, wre_ext);
    ce64_k<<<24576, 256, 0, stream>>>(char_ids, char_emb, ce_hi, ce_lo);
    wv_k<<<3072, 256, 0, stream>>>(word_ids, word_emb, enc_in);
    conv_k<<<192, 256, 0, stream>>>((const ushort*)ce_hi, (const ushort*)ce_lo,
                                    (const ushort*)wre_ext, conv_b, enc_in);
    eisplit_k<<<4608, 256, 0, stream>>>(enc_in, ei_hi, ei_lo);
    wsplit_k<<<384, 256, 0, stream>>>(fw_wih, wfw_ext, 512, 512, 192);
    wsplit_k<<<384, 256, 0, stream>>>(bw_wih, wbw_ext, 512, 512, 192);

    // ---- LSTM input gates (MFMA), then recurrence ----
    gemm3_k<0,0,192><<<dim3(48,4), 256, 0, stream>>>((const ushort*)ei_hi, (const ushort*)ei_lo,
        (const ushort*)wfw_ext, (const ushort*)(wfw_ext + 512*192), fw_b, gi2,
        nullptr, nullptr, 512, 512);
    gemm3_k<0,0,192><<<dim3(48,4), 256, 0, stream>>>((const ushort*)ei_hi, (const ushort*)ei_lo,
        (const ushort*)wbw_ext, (const ushort*)(wbw_ext + 512*192), bw_b, gi2 + (size_t)NROWS*512,
        nullptr, nullptr, 512, 512);
    whht_k<<<512, 256, 0, stream>>>(fw_whh, bw_whh, whht);
    lstm_k<<<128, 1024, 0, stream>>>(gi2, whht, enc_hi, enc_lo);

    // ---- heads (MFMA) + decode prep ----
    cmbsplit_k<<<1024, 256, 0, stream>>>(gru_whh, proj_w, gru_bhh, proj_b, cmb_ext, cmb_bias);
    wsplit_k<<<640, 256, 0, stream>>>(tag_w, tag_ext, 600, 640, 256);
    wsplit_k<<<256, 256, 0, stream>>>(init_w, init_ext, 256, 256, 256);
    gitab_k<<<600, 256, 0, stream>>>(lemma_emb, gru_wih, gru_bih, git);
    gemm3_k<0,0,256><<<dim3(48,5), 256, 0, stream>>>((const ushort*)enc_hi, (const ushort*)enc_lo,
        (const ushort*)tag_ext, (const ushort*)(tag_ext + 640*256), tag_b, out_tag,
        nullptr, nullptr, NTAGS, NTAGS);
    gemm3_k<1,1,256><<<dim3(48,2), 256, 0, stream>>>((const ushort*)enc_hi, (const ushort*)enc_lo,
        (const ushort*)init_ext, (const ushort*)(init_ext + 256*256), init_b, hdec,
        (ushort*)h_hi, (ushort*)h_lo, 256, 256);

    // ---- greedy GRU decode: 24 x {combined GEMM (one-round grid), argmax+update} + final ----
    const ushort* cmb_hi = (const ushort*)cmb_ext;
    const ushort* cmb_lo = cmb_hi + 1024 * 256;
    for (int s = 0; s < LMAXD; ++s) {
        float* lem = (s > 0) ? (out_lem + (size_t)(s - 1) * VCD) : nullptr;
        gemmC_k<<<dim3(96,8), 256, 0, stream>>>((const ushort*)h_hi, (const ushort*)h_lo,
            cmb_hi, cmb_lo, cmb_bias, gh, lem);
        argupd_k<<<NROWS, 256, 0, stream>>>(gh, git, lem, hdec, (ushort*)h_hi, (ushort*)h_lo);
    }
    // final step: same combined GEMM writes logits_23 (gh_25 recomputed into scratch, unused)
    gemmC_k<<<dim3(96,8), 256, 0, stream>>>((const ushort*)h_hi, (const ushort*)h_lo,
        cmb_hi, cmb_lo, cmb_bias, gh, out_lem + (size_t)(LMAXD - 1) * VCD);
}